// Round 7
// baseline (197.566 us; speedup 1.0000x reference)
//
#include <hip/hip_runtime.h>
#include <math.h>

#define T_STEPS 1000
#define B_ROWS 65536
#define N_FCAT 24
#define N_DCAT 298
#define NUM_NUM 16
#define MO_STRIDE 314
#define NKID 14
#define NEGL -69.07755278982137f   // log(float32(1e-30))
#define NINF -1e38f

__constant__ int c_numc[N_FCAT] = {2,2,3,4,5,6,8,10,10,12,16,16,20,24,32,40,2,3,4,5,6,8,10,50};
__constant__ int c_kval[NKID]   = {2,3,4,5,6,8,10,12,16,20,24,32,40,50};

// persistent module-owned tables, rebuilt deterministically every launch
__device__ float  g_sched[4*T_STEPS];      // LA | L1A | LCA | L1CA
__device__ float  g_ecap[T_STEPS];         // exp(LCA[t-1]) (1.0 at t=0)
__device__ float4 g_tab4[T_STEPS*NKID*3];  // per (t,kidx): 12 floats
__device__ float  g_klp;                   // sum over features of kl_prior

__device__ __forceinline__ float lae(float a, float b) {   // precise f32 (argmax path)
  float m = fmaxf(a, b);
  return m + logf(expf(a - m) + expf(b - m));
}
__device__ __forceinline__ double lad(double a, double b) {
  double m = fmax(a, b);
  return m + log(exp(a - m) + exp(b - m));
}

__global__ void build_sched_kernel() {
  __shared__ double sh[1024];
  int i = threadIdx.x;
  double la = 0.0;
  if (i < T_STEPS) {
    const double PI = 3.14159265358979323846;
    double u0 = (double)i / 1000.0, u1 = (double)(i + 1) / 1000.0;
    double c0 = cos((u0 + 0.008) / 1.008 * PI * 0.5);
    double c1 = cos((u1 + 0.008) / 1.008 * PI * 0.5);
    double beta = 1.0 - (c1 * c1) / (c0 * c0);
    if (beta > 0.2) beta = 0.2;
    la = log(1.0 - beta);
  }
  sh[i] = la;
  __syncthreads();
  double run = la;
  for (int ofs = 1; ofs < 1024; ofs <<= 1) {
    double add = (i >= ofs) ? sh[i - ofs] : 0.0;
    __syncthreads();
    run += add;
    sh[i] = run;
    __syncthreads();
  }
  if (i < T_STEPS) {
    g_sched[i]               = (float)la;
    g_sched[T_STEPS + i]     = (float)log(-expm1(la));
    g_sched[2 * T_STEPS + i] = (float)run;
    g_sched[3 * T_STEPS + i] = (float)log(-expm1(run));
  }
}

__global__ void build_tab_kernel() {
  int e = blockIdx.x * blockDim.x + threadIdx.x;
  if (e < T_STEPS * NKID) {
    int t = e / NKID, k = e - t * NKID;
    bool t0 = (t == 0);
    int tm1 = t0 ? 0 : t - 1;
    float la = g_sched[t], l1a = g_sched[T_STEPS + t];
    float lca = g_sched[2 * T_STEPS + t], l1ca = g_sched[3 * T_STEPS + t];
    float lca_p = g_sched[2 * T_STEPS + tm1], l1ca_p = g_sched[3 * T_STEPS + tm1];
    float logK = (float)log((double)c_kval[k]);
    // ---- argmax-critical: identical f32 sequence to the verified round-1 kernel ----
    float cb_t = l1ca - logK;
    float ev_h = lae(lca, cb_t);
    float ev_n = lae(NEGL + lca, cb_t);
    // ---- value path: double precision ----
    double cb1 = (double)l1a - (double)logK;
    double q1h = lad((double)la, cb1);
    double q1n = lad((double)NEGL + (double)la, cb1);
    double cbp = (double)l1ca_p - (double)logK;
    double levth = t0 ? 0.0 : lad((double)lca_p, cbp);
    double levtn = t0 ? (double)NEGL : lad((double)NEGL + (double)lca_p, cbp);
    float4* o = g_tab4 + e * 3;
    o[0] = make_float4(ev_h, ev_n, (float)q1h, (float)q1n);
    o[1] = make_float4((float)exp(q1h), (float)exp(q1n), (float)exp(levth), (float)exp(levtn));
    o[2] = make_float4((float)levth, (float)levtn, t0 ? 0.f : (float)exp(cbp), 0.f);
    if (k == 0) g_ecap[t] = t0 ? 1.f : (float)exp((double)lca_p);
  }
  if (e == 0) {
    double lcaT = g_sched[2 * T_STEPS + T_STEPS - 1];
    double l1caT = g_sched[3 * T_STEPS + T_STEPS - 1];
    double s = 0.0;
    for (int f = 0; f < N_FCAT; ++f) {
      double logK = log((double)c_numc[f]);
      double cbT = l1caT - logK;
      double qh = lad(lcaT, cbT);
      double qn = lad((double)NEGL + lcaT, cbT);
      s += exp(qh) * (qh + logK) + (double)(c_numc[f] - 1) * exp(qn) * (qn + logK);
    }
    g_klp = (float)s;
  }
}

// ---- 8-lane reductions via DPP: quad_perm xor1 (0xB1), xor2 (0x4E), row_half_mirror (0x141) ----
__device__ __forceinline__ float osum(float v) {
  v += __int_as_float(__builtin_amdgcn_mov_dpp(__float_as_int(v), 0xB1, 0xF, 0xF, true));
  v += __int_as_float(__builtin_amdgcn_mov_dpp(__float_as_int(v), 0x4E, 0xF, 0xF, true));
  v += __int_as_float(__builtin_amdgcn_mov_dpp(__float_as_int(v), 0x141, 0xF, 0xF, true));
  return v;
}
__device__ __forceinline__ void oargmax(float& smax, int& jm) {
  float os; int oj;
  os = __int_as_float(__builtin_amdgcn_mov_dpp(__float_as_int(smax), 0xB1, 0xF, 0xF, true));
  oj = __builtin_amdgcn_mov_dpp(jm, 0xB1, 0xF, 0xF, true);
  if (os > smax || (os == smax && oj < jm)) { smax = os; jm = oj; }
  os = __int_as_float(__builtin_amdgcn_mov_dpp(__float_as_int(smax), 0x4E, 0xF, 0xF, true));
  oj = __builtin_amdgcn_mov_dpp(jm, 0x4E, 0xF, 0xF, true);
  if (os > smax || (os == smax && oj < jm)) { smax = os; jm = oj; }
  os = __int_as_float(__builtin_amdgcn_mov_dpp(__float_as_int(smax), 0x141, 0xF, 0xF, true));
  oj = __builtin_amdgcn_mov_dpp(jm, 0x141, 0xF, 0xF, true);
  if (os > smax || (os == smax && oj < jm)) { smax = os; jm = oj; }
}

// One feature with compile-time K. Decision path (clip -> precise logf gumbel ->
// score select -> ascending-j strict-> argmax, min-index cross-lane) is
// bit-identical to the verified round-1/2/4/5 kernels.
// CACHE: for small K the exp(x) values are register-cached across the two
// passes; for the largest K (NJ>5) pass 2 reloads x (L1-hit) and recomputes
// __expf (identical input -> identical value) to cap peak register pressure.
template <int K>
__device__ __forceinline__ float feat_body(int g, int off, int h, bool t0, float ecap,
                                           const float* __restrict__ mocat,
                                           const float* __restrict__ urow,
                                           float4 ta, float4 tbv, float4 tc)
{
  constexpr int NJ = (K + 7) / 8;
  constexpr bool CACHE = (NJ <= 5);
  float ev_h = ta.x, ev_n = ta.y, q1h = ta.z, q1n = ta.w;
  float q1he = tbv.x, q1ne = tbv.y, eth = tbv.z, etn = tbv.w;
  float levth = tc.x, levtn = tc.y, cbpe = tc.z;

  float xv[CACHE ? NJ : 1];

  // ---- pass 1: sum exp(model_out) + gumbel-score argmax ----
  float s1 = 0.f, smax = NINF;
  int jm = 0x7fffffff;
  #pragma unroll
  for (int jj = 0; jj < NJ; ++jj) {
    int j = jj * 8 + g;
    int jc = (j < K) ? j : (K - 1);
    bool in = (j < K);
    float e = __expf(mocat[off + jc]);
    if (CACHE) xv[jj] = e;                    // cache exp for pass 2
    s1 += in ? e : 0.f;
    float u = urow[off + jc];
    u = fminf(fmaxf(u, 1e-30f), 1.0f);
    float gum = -logf(-logf(u));
    float sc = ((j == h) ? ev_h : ev_n) + gum;
    if (in && sc > smax) { smax = sc; jm = j; }
  }
  s1 = osum(s1);
  oargmax(smax, jm);

  float ca = ecap * __builtin_amdgcn_rcpf(s1);  // exp(lca_{t-1}) / sum(exp(mocat))

  // ---- pass 2: E_j = exp(lev_m_j); linear-space accumulation ----
  float Sm = 0.f, Bv = 0.f, lmh = 0.f;
  #pragma unroll
  for (int jj = 0; jj < NJ; ++jj) {
    int j = jj * 8 + g;
    int jc = (j < K) ? j : (K - 1);
    bool in = (j < K);
    float e = CACHE ? xv[jj] : __expf(mocat[off + jc]);
    float E = fmaf(e, ca, cbpe);             // e^{lr+lca_p} + e^{cb_p}
    float lm = __logf(E);                    // lev_m_j
    float qe = (j == jm) ? q1he : q1ne;      // e^{q1_j}
    Sm = in ? fmaf(E, qe, Sm) : Sm;          // sum e^{un_m}
    float c = ((j == h) ? eth : etn) * qe;   // e^{un_t_j}
    Bv = in ? fmaf(c, lm, Bv) : Bv;          // sum e^{un_t} * lev_m
    lmh += (in && j == h) ? lm : 0.f;
  }
  Sm = osum(Sm); Bv = osum(Bv); lmh = osum(lmh);

  float lse_m = __logf(Sm);
  bool hm = (h == jm);
  float Kf2 = (float)K - 2.f + (hm ? 1.f : 0.f);
  float coefH = eth * (hm ? q1he : q1ne);
  float coefJ = hm ? 0.f : etn * q1he;
  float cn = etn * q1ne;
  float A  = cn * levtn * Kf2 + coefH * levth + coefJ * levtn;  // sum e^{un_t} * levt
  float St = cn * Kf2 + coefH + coefJ;                          // sum e^{un_t}
  float kl = (A - Bv) * __builtin_amdgcn_rcpf(St) - __logf(St) + lse_m;
  float unh = lmh + (hm ? q1h : q1n);
  float dec = lse_m - unh;
  return t0 ? dec : kl;
}

// One K-class: hoist the table loads, loop members at runtime (no extra inlining)
template <int K, int KID, int NM>
__device__ __forceinline__ float do_group(int g, const int (&OS)[NM], const int (&FS)[NM],
                                          const int* __restrict__ xrow, bool t0, float ecap,
                                          const float* __restrict__ mocat,
                                          const float* __restrict__ urow,
                                          const float4* __restrict__ tabt)
{
  const float4* tb = tabt + KID * 3;
  float4 ta = tb[0], tbv = tb[1], tc = tb[2];
  float acc = 0.f;
  #pragma unroll 1
  for (int i = 0; i < NM; ++i)
    acc += feat_body<K>(g, OS[i], xrow[FS[i]], t0, ecap, mocat, urow, ta, tbv, tc);
  return acc;
}

__global__ __launch_bounds__(256, 7) void gmd_kernel(
    const int* __restrict__ xci, const int* __restrict__ tarr,
    const float* __restrict__ noise, const float* __restrict__ ucat,
    const float* __restrict__ mo, float* __restrict__ out)
{
  int tid = blockIdx.x * blockDim.x + threadIdx.x;
  int row = tid >> 3;   // 8 threads per row
  int g   = tid & 7;
  if (row >= B_ROWS) return;

  int t = tarr[row];
  bool t0 = (t == 0);
  float ecap = g_ecap[t];
  const float4* tabt = g_tab4 + (size_t)t * NKID * 3;
  const int* xrow = xci + (size_t)row * N_FCAT;

  const float* morow = mo + (size_t)row * MO_STRIDE;
  const float* mocat = morow + NUM_NUM;
  const float* urow  = ucat + (size_t)row * N_DCAT;

  // Gaussian part: 2 of 16 elements per lane
  float gauss;
  {
    float2 nv = ((const float2*)(noise + (size_t)row * NUM_NUM))[g];
    float2 mv = ((const float2*)morow)[g];
    float d0 = nv.x - mv.x, d1 = nv.y - mv.y;
    gauss = fmaf(d0, d0, d1 * d1);
  }

  float multi = 0.f;
  {
    static constexpr int OS[3] = {0, 2, 210}, FS[3] = {0, 1, 16};
    multi += do_group<2, 0>(g, OS, FS, xrow, t0, ecap, mocat, urow, tabt);
  }
  {
    static constexpr int OS[2] = {4, 212}, FS[2] = {2, 17};
    multi += do_group<3, 1>(g, OS, FS, xrow, t0, ecap, mocat, urow, tabt);
  }
  {
    static constexpr int OS[2] = {7, 215}, FS[2] = {3, 18};
    multi += do_group<4, 2>(g, OS, FS, xrow, t0, ecap, mocat, urow, tabt);
  }
  {
    static constexpr int OS[2] = {11, 219}, FS[2] = {4, 19};
    multi += do_group<5, 3>(g, OS, FS, xrow, t0, ecap, mocat, urow, tabt);
  }
  {
    static constexpr int OS[2] = {16, 224}, FS[2] = {5, 20};
    multi += do_group<6, 4>(g, OS, FS, xrow, t0, ecap, mocat, urow, tabt);
  }
  {
    static constexpr int OS[2] = {22, 230}, FS[2] = {6, 21};
    multi += do_group<8, 5>(g, OS, FS, xrow, t0, ecap, mocat, urow, tabt);
  }
  {
    static constexpr int OS[3] = {30, 40, 238}, FS[3] = {7, 8, 22};
    multi += do_group<10, 6>(g, OS, FS, xrow, t0, ecap, mocat, urow, tabt);
  }
  {
    static constexpr int OS[1] = {50}, FS[1] = {9};
    multi += do_group<12, 7>(g, OS, FS, xrow, t0, ecap, mocat, urow, tabt);
  }
  {
    static constexpr int OS[2] = {62, 78}, FS[2] = {10, 11};
    multi += do_group<16, 8>(g, OS, FS, xrow, t0, ecap, mocat, urow, tabt);
  }
  {
    static constexpr int OS[1] = {94}, FS[1] = {12};
    multi += do_group<20, 9>(g, OS, FS, xrow, t0, ecap, mocat, urow, tabt);
  }
  {
    static constexpr int OS[1] = {114}, FS[1] = {13};
    multi += do_group<24, 10>(g, OS, FS, xrow, t0, ecap, mocat, urow, tabt);
  }
  {
    static constexpr int OS[1] = {138}, FS[1] = {14};
    multi += do_group<32, 11>(g, OS, FS, xrow, t0, ecap, mocat, urow, tabt);
  }
  {
    static constexpr int OS[1] = {170}, FS[1] = {15};
    multi += do_group<40, 12>(g, OS, FS, xrow, t0, ecap, mocat, urow, tabt);
  }
  {
    static constexpr int OS[1] = {248}, FS[1] = {23};
    multi += do_group<50, 13>(g, OS, FS, xrow, t0, ecap, mocat, urow, tabt);
  }

  gauss = osum(gauss);
  if (g == 0) out[row] = (multi * 1000.f + g_klp) / 24.f + gauss / 16.f;
}

extern "C" void kernel_launch(void* const* d_in, const int* in_sizes, int n_in,
                              void* d_out, int out_size, void* d_ws, size_t ws_size,
                              hipStream_t stream) {
  const int*   xci   = (const int*)d_in[0];
  const int*   tarr  = (const int*)d_in[1];
  const float* noise = (const float*)d_in[2];
  const float* ucat  = (const float*)d_in[3];
  const float* mo    = (const float*)d_in[4];
  float* out = (float*)d_out;
  (void)d_ws; (void)ws_size;

  hipLaunchKernelGGL(build_sched_kernel, dim3(1), dim3(1024), 0, stream);
  hipLaunchKernelGGL(build_tab_kernel, dim3((T_STEPS * NKID + 255) / 256), dim3(256), 0, stream);
  hipLaunchKernelGGL(gmd_kernel, dim3((B_ROWS * 8) / 256), dim3(256), 0, stream,
                     xci, tarr, noise, ucat, mo, out);
}

// Round 8
// 129.402 us; speedup vs baseline: 1.5268x; 1.5268x over previous
//
#include <hip/hip_runtime.h>
#include <math.h>

#define T_STEPS 1000
#define B_ROWS 65536
#define N_FCAT 24
#define N_DCAT 298
#define NUM_NUM 16
#define MO_STRIDE 314
#define NKID 14
#define NEGL -69.07755278982137f   // log(float32(1e-30))
#define NINF -1e38f

__constant__ int c_numc[N_FCAT] = {2,2,3,4,5,6,8,10,10,12,16,16,20,24,32,40,2,3,4,5,6,8,10,50};
__constant__ int c_kval[NKID]   = {2,3,4,5,6,8,10,12,16,20,24,32,40,50};

// persistent module-owned tables, rebuilt deterministically every launch
__device__ float  g_sched[4*T_STEPS];      // LA | L1A | LCA | L1CA
__device__ float  g_ecap[T_STEPS];         // exp(LCA[t-1]) (1.0 at t=0)
__device__ float4 g_tab4[T_STEPS*NKID*3];  // per (t,kidx): 12 floats, phase-ordered
__device__ float  g_klp;                   // sum over features of kl_prior

__device__ __forceinline__ float lae(float a, float b) {   // precise f32 (argmax path)
  float m = fmaxf(a, b);
  return m + logf(expf(a - m) + expf(b - m));
}
__device__ __forceinline__ double lad(double a, double b) {
  double m = fmax(a, b);
  return m + log(exp(a - m) + exp(b - m));
}

__global__ void build_sched_kernel() {
  __shared__ double sh[1024];
  int i = threadIdx.x;
  double la = 0.0;
  if (i < T_STEPS) {
    const double PI = 3.14159265358979323846;
    double u0 = (double)i / 1000.0, u1 = (double)(i + 1) / 1000.0;
    double c0 = cos((u0 + 0.008) / 1.008 * PI * 0.5);
    double c1 = cos((u1 + 0.008) / 1.008 * PI * 0.5);
    double beta = 1.0 - (c1 * c1) / (c0 * c0);
    if (beta > 0.2) beta = 0.2;
    la = log(1.0 - beta);
  }
  sh[i] = la;
  __syncthreads();
  double run = la;
  for (int ofs = 1; ofs < 1024; ofs <<= 1) {
    double add = (i >= ofs) ? sh[i - ofs] : 0.0;
    __syncthreads();
    run += add;
    sh[i] = run;
    __syncthreads();
  }
  if (i < T_STEPS) {
    g_sched[i]               = (float)la;
    g_sched[T_STEPS + i]     = (float)log(-expm1(la));
    g_sched[2 * T_STEPS + i] = (float)run;
    g_sched[3 * T_STEPS + i] = (float)log(-expm1(run));
  }
}

__global__ void build_tab_kernel() {
  int e = blockIdx.x * blockDim.x + threadIdx.x;
  if (e < T_STEPS * NKID) {
    int t = e / NKID, k = e - t * NKID;
    bool t0 = (t == 0);
    int tm1 = t0 ? 0 : t - 1;
    float la = g_sched[t], l1a = g_sched[T_STEPS + t];
    float lca = g_sched[2 * T_STEPS + t], l1ca = g_sched[3 * T_STEPS + t];
    float lca_p = g_sched[2 * T_STEPS + tm1], l1ca_p = g_sched[3 * T_STEPS + tm1];
    float logK = (float)log((double)c_kval[k]);
    // ---- argmax-critical: identical f32 sequence to the verified round-1 kernel ----
    float cb_t = l1ca - logK;
    float ev_h = lae(lca, cb_t);
    float ev_n = lae(NEGL + lca, cb_t);
    // ---- value path: double precision ----
    double cb1 = (double)l1a - (double)logK;
    double q1h = lad((double)la, cb1);
    double q1n = lad((double)NEGL + (double)la, cb1);
    double cbp = (double)l1ca_p - (double)logK;
    double levth = t0 ? 0.0 : lad((double)lca_p, cbp);
    double levtn = t0 ? (double)NEGL : lad((double)NEGL + (double)lca_p, cbp);
    float4* o = g_tab4 + e * 3;
    // phase-ordered: [0] pass-1 consts, [1] pass-2 consts, [2] epilogue consts
    o[0] = make_float4(ev_h, ev_n, t0 ? 0.f : (float)exp(cbp), 0.f);
    o[1] = make_float4((float)exp(q1h), (float)exp(q1n), (float)exp(levth), (float)exp(levtn));
    o[2] = make_float4((float)levth, (float)levtn, (float)q1h, (float)q1n);
    if (k == 0) g_ecap[t] = t0 ? 1.f : (float)exp((double)lca_p);
  }
  if (e == 0) {
    double lcaT = g_sched[2 * T_STEPS + T_STEPS - 1];
    double l1caT = g_sched[3 * T_STEPS + T_STEPS - 1];
    double s = 0.0;
    for (int f = 0; f < N_FCAT; ++f) {
      double logK = log((double)c_numc[f]);
      double cbT = l1caT - logK;
      double qh = lad(lcaT, cbT);
      double qn = lad((double)NEGL + lcaT, cbT);
      s += exp(qh) * (qh + logK) + (double)(c_numc[f] - 1) * exp(qn) * (qn + logK);
    }
    g_klp = (float)s;
  }
}

// ---- 8-lane reductions via DPP: quad_perm xor1 (0xB1), xor2 (0x4E), row_half_mirror (0x141) ----
__device__ __forceinline__ float osum(float v) {
  v += __int_as_float(__builtin_amdgcn_mov_dpp(__float_as_int(v), 0xB1, 0xF, 0xF, true));
  v += __int_as_float(__builtin_amdgcn_mov_dpp(__float_as_int(v), 0x4E, 0xF, 0xF, true));
  v += __int_as_float(__builtin_amdgcn_mov_dpp(__float_as_int(v), 0x141, 0xF, 0xF, true));
  return v;
}
__device__ __forceinline__ void oargmax(float& smax, int& jm) {
  float os; int oj;
  os = __int_as_float(__builtin_amdgcn_mov_dpp(__float_as_int(smax), 0xB1, 0xF, 0xF, true));
  oj = __builtin_amdgcn_mov_dpp(jm, 0xB1, 0xF, 0xF, true);
  if (os > smax || (os == smax && oj < jm)) { smax = os; jm = oj; }
  os = __int_as_float(__builtin_amdgcn_mov_dpp(__float_as_int(smax), 0x4E, 0xF, 0xF, true));
  oj = __builtin_amdgcn_mov_dpp(jm, 0x4E, 0xF, 0xF, true);
  if (os > smax || (os == smax && oj < jm)) { smax = os; jm = oj; }
  os = __int_as_float(__builtin_amdgcn_mov_dpp(__float_as_int(smax), 0x141, 0xF, 0xF, true));
  oj = __builtin_amdgcn_mov_dpp(jm, 0x141, 0xF, 0xF, true);
  if (os > smax || (os == smax && oj < jm)) { smax = os; jm = oj; }
}

// One feature with compile-time K. Decision path (clip -> precise logf gumbel ->
// score select -> ascending-j strict-max, min-index cross-lane) is bit-identical
// to the verified round-1/2/4/5 kernels.
// Register discipline: exp(x) is register-cached across passes only for NJ<=2
// (K<=16); larger K reloads x (L1-hit) and recomputes __expf (identical input
// -> identical value). Table float4s are loaded phase-locally to shorten live
// ranges. Goal: natural VGPR <= 64 (occupancy tier), NO launch-bounds cap
// (a cap on this body spills catastrophically -- rounds 6/7).
template <int K>
__device__ __forceinline__ float feat_body(int g, int off, int h, bool t0, float ecap,
                                           const float* __restrict__ mocat,
                                           const float* __restrict__ urow,
                                           const float4* __restrict__ tb)
{
  constexpr int NJ = (K + 7) / 8;
  constexpr bool CACHE = (NJ <= 2);

  float4 ta = tb[0];                       // ev_h, ev_n, cbpe
  float xv[CACHE ? NJ : 1];

  // ---- pass 1: sum exp(model_out) + gumbel-score argmax ----
  float s1 = 0.f, smax = NINF;
  int jm = 0x7fffffff;
  #pragma unroll
  for (int jj = 0; jj < NJ; ++jj) {
    int j = jj * 8 + g;
    int jc = (j < K) ? j : (K - 1);
    bool in = (j < K);
    float e = __expf(mocat[off + jc]);
    if (CACHE) xv[jj] = e;                    // cache exp for pass 2
    s1 += in ? e : 0.f;
    float u = urow[off + jc];
    u = fminf(fmaxf(u, 1e-30f), 1.0f);
    float gum = -logf(-logf(u));
    float sc = ((j == h) ? ta.x : ta.y) + gum;
    if (in && sc > smax) { smax = sc; jm = j; }
  }
  s1 = osum(s1);
  oargmax(smax, jm);

  float ca = ecap * __builtin_amdgcn_rcpf(s1);  // exp(lca_{t-1}) / sum(exp(mocat))
  float cbpe = ta.z;
  float4 tbv = tb[1];                      // q1he, q1ne, eth, etn

  // ---- pass 2: E_j = exp(lev_m_j); linear-space accumulation ----
  float Sm = 0.f, Bv = 0.f, lmh = 0.f;
  #pragma unroll
  for (int jj = 0; jj < NJ; ++jj) {
    int j = jj * 8 + g;
    int jc = (j < K) ? j : (K - 1);
    bool in = (j < K);
    float e = CACHE ? xv[jj] : __expf(mocat[off + jc]);
    float E = fmaf(e, ca, cbpe);             // e^{lr+lca_p} + e^{cb_p}
    float lm = __logf(E);                    // lev_m_j
    float qe = (j == jm) ? tbv.x : tbv.y;    // e^{q1_j}
    Sm = in ? fmaf(E, qe, Sm) : Sm;          // sum e^{un_m}
    float c = ((j == h) ? tbv.z : tbv.w) * qe;  // e^{un_t_j}
    Bv = in ? fmaf(c, lm, Bv) : Bv;          // sum e^{un_t} * lev_m
    lmh += (in && j == h) ? lm : 0.f;
  }
  Sm = osum(Sm); Bv = osum(Bv); lmh = osum(lmh);

  float4 tc = tb[2];                       // levth, levtn, q1h, q1n
  float lse_m = __logf(Sm);
  bool hm = (h == jm);
  float Kf2 = (float)K - 2.f + (hm ? 1.f : 0.f);
  float coefH = tbv.z * (hm ? tbv.x : tbv.y);
  float coefJ = hm ? 0.f : tbv.w * tbv.x;
  float cn = tbv.w * tbv.y;
  float A  = cn * tc.y * Kf2 + coefH * tc.x + coefJ * tc.y;   // sum e^{un_t} * levt
  float St = cn * Kf2 + coefH + coefJ;                        // sum e^{un_t}
  float kl = (A - Bv) * __builtin_amdgcn_rcpf(St) - __logf(St) + lse_m;
  float unh = lmh + (hm ? tc.z : tc.w);
  float dec = lse_m - unh;
  return t0 ? dec : kl;
}

// One K-class: loop members at runtime (no extra inlining); table float4s are
// loaded inside feat_body phase-locally.
template <int K, int KID, int NM>
__device__ __forceinline__ float do_group(int g, const int (&OS)[NM], const int (&FS)[NM],
                                          const int* __restrict__ xrow, bool t0, float ecap,
                                          const float* __restrict__ mocat,
                                          const float* __restrict__ urow,
                                          const float4* __restrict__ tabt)
{
  const float4* tb = tabt + KID * 3;
  float acc = 0.f;
  #pragma unroll 1
  for (int i = 0; i < NM; ++i)
    acc += feat_body<K>(g, OS[i], xrow[FS[i]], t0, ecap, mocat, urow, tb);
  return acc;
}

__global__ __launch_bounds__(256) void gmd_kernel(
    const int* __restrict__ xci, const int* __restrict__ tarr,
    const float* __restrict__ noise, const float* __restrict__ ucat,
    const float* __restrict__ mo, float* __restrict__ out)
{
  int tid = blockIdx.x * blockDim.x + threadIdx.x;
  int row = tid >> 3;   // 8 threads per row
  int g   = tid & 7;
  if (row >= B_ROWS) return;

  int t = tarr[row];
  bool t0 = (t == 0);
  float ecap = g_ecap[t];
  const float4* tabt = g_tab4 + (size_t)t * NKID * 3;
  const int* xrow = xci + (size_t)row * N_FCAT;

  const float* morow = mo + (size_t)row * MO_STRIDE;
  const float* mocat = morow + NUM_NUM;
  const float* urow  = ucat + (size_t)row * N_DCAT;

  // Gaussian part: 2 of 16 elements per lane
  float gauss;
  {
    float2 nv = ((const float2*)(noise + (size_t)row * NUM_NUM))[g];
    float2 mv = ((const float2*)morow)[g];
    float d0 = nv.x - mv.x, d1 = nv.y - mv.y;
    gauss = fmaf(d0, d0, d1 * d1);
  }

  float multi = 0.f;
  {
    static constexpr int OS[3] = {0, 2, 210}, FS[3] = {0, 1, 16};
    multi += do_group<2, 0>(g, OS, FS, xrow, t0, ecap, mocat, urow, tabt);
  }
  {
    static constexpr int OS[2] = {4, 212}, FS[2] = {2, 17};
    multi += do_group<3, 1>(g, OS, FS, xrow, t0, ecap, mocat, urow, tabt);
  }
  {
    static constexpr int OS[2] = {7, 215}, FS[2] = {3, 18};
    multi += do_group<4, 2>(g, OS, FS, xrow, t0, ecap, mocat, urow, tabt);
  }
  {
    static constexpr int OS[2] = {11, 219}, FS[2] = {4, 19};
    multi += do_group<5, 3>(g, OS, FS, xrow, t0, ecap, mocat, urow, tabt);
  }
  {
    static constexpr int OS[2] = {16, 224}, FS[2] = {5, 20};
    multi += do_group<6, 4>(g, OS, FS, xrow, t0, ecap, mocat, urow, tabt);
  }
  {
    static constexpr int OS[2] = {22, 230}, FS[2] = {6, 21};
    multi += do_group<8, 5>(g, OS, FS, xrow, t0, ecap, mocat, urow, tabt);
  }
  {
    static constexpr int OS[3] = {30, 40, 238}, FS[3] = {7, 8, 22};
    multi += do_group<10, 6>(g, OS, FS, xrow, t0, ecap, mocat, urow, tabt);
  }
  {
    static constexpr int OS[1] = {50}, FS[1] = {9};
    multi += do_group<12, 7>(g, OS, FS, xrow, t0, ecap, mocat, urow, tabt);
  }
  {
    static constexpr int OS[2] = {62, 78}, FS[2] = {10, 11};
    multi += do_group<16, 8>(g, OS, FS, xrow, t0, ecap, mocat, urow, tabt);
  }
  {
    static constexpr int OS[1] = {94}, FS[1] = {12};
    multi += do_group<20, 9>(g, OS, FS, xrow, t0, ecap, mocat, urow, tabt);
  }
  {
    static constexpr int OS[1] = {114}, FS[1] = {13};
    multi += do_group<24, 10>(g, OS, FS, xrow, t0, ecap, mocat, urow, tabt);
  }
  {
    static constexpr int OS[1] = {138}, FS[1] = {14};
    multi += do_group<32, 11>(g, OS, FS, xrow, t0, ecap, mocat, urow, tabt);
  }
  {
    static constexpr int OS[1] = {170}, FS[1] = {15};
    multi += do_group<40, 12>(g, OS, FS, xrow, t0, ecap, mocat, urow, tabt);
  }
  {
    static constexpr int OS[1] = {248}, FS[1] = {23};
    multi += do_group<50, 13>(g, OS, FS, xrow, t0, ecap, mocat, urow, tabt);
  }

  gauss = osum(gauss);
  if (g == 0) out[row] = (multi * 1000.f + g_klp) / 24.f + gauss / 16.f;
}

extern "C" void kernel_launch(void* const* d_in, const int* in_sizes, int n_in,
                              void* d_out, int out_size, void* d_ws, size_t ws_size,
                              hipStream_t stream) {
  const int*   xci   = (const int*)d_in[0];
  const int*   tarr  = (const int*)d_in[1];
  const float* noise = (const float*)d_in[2];
  const float* ucat  = (const float*)d_in[3];
  const float* mo    = (const float*)d_in[4];
  float* out = (float*)d_out;
  (void)d_ws; (void)ws_size;

  hipLaunchKernelGGL(build_sched_kernel, dim3(1), dim3(1024), 0, stream);
  hipLaunchKernelGGL(build_tab_kernel, dim3((T_STEPS * NKID + 255) / 256), dim3(256), 0, stream);
  hipLaunchKernelGGL(gmd_kernel, dim3((B_ROWS * 8) / 256), dim3(256), 0, stream,
                     xci, tarr, noise, ucat, mo, out);
}

// Round 9
// 129.375 us; speedup vs baseline: 1.5271x; 1.0002x over previous
//
#include <hip/hip_runtime.h>
#include <math.h>

#define T_STEPS 1000
#define B_ROWS 65536
#define N_FCAT 24
#define N_DCAT 298
#define NUM_NUM 16
#define MO_STRIDE 314
#define NKID 14
#define NEGL -69.07755278982137f   // log(float32(1e-30))
#define NINF -1e38f

__constant__ int c_numc[N_FCAT] = {2,2,3,4,5,6,8,10,10,12,16,16,20,24,32,40,2,3,4,5,6,8,10,50};
__constant__ int c_kval[NKID]   = {2,3,4,5,6,8,10,12,16,20,24,32,40,50};

// persistent module-owned tables, rebuilt deterministically every launch
__device__ float  g_sched[4*T_STEPS];      // LA | L1A | LCA | L1CA
__device__ float  g_ecap[T_STEPS];         // exp(LCA[t-1]) (1.0 at t=0)
__device__ float4 g_tab4[T_STEPS*NKID*3];  // per (t,kidx): 12 floats
__device__ float  g_klp;                   // sum over features of kl_prior

__device__ __forceinline__ float lae(float a, float b) {   // precise f32 (argmax path)
  float m = fmaxf(a, b);
  return m + logf(expf(a - m) + expf(b - m));
}
__device__ __forceinline__ double lad(double a, double b) {
  double m = fmax(a, b);
  return m + log(exp(a - m) + exp(b - m));
}

__global__ void build_sched_kernel() {
  __shared__ double sh[1024];
  int i = threadIdx.x;
  double la = 0.0;
  if (i < T_STEPS) {
    const double PI = 3.14159265358979323846;
    double u0 = (double)i / 1000.0, u1 = (double)(i + 1) / 1000.0;
    double c0 = cos((u0 + 0.008) / 1.008 * PI * 0.5);
    double c1 = cos((u1 + 0.008) / 1.008 * PI * 0.5);
    double beta = 1.0 - (c1 * c1) / (c0 * c0);
    if (beta > 0.2) beta = 0.2;
    la = log(1.0 - beta);
  }
  sh[i] = la;
  __syncthreads();
  double run = la;
  for (int ofs = 1; ofs < 1024; ofs <<= 1) {
    double add = (i >= ofs) ? sh[i - ofs] : 0.0;
    __syncthreads();
    run += add;
    sh[i] = run;
    __syncthreads();
  }
  if (i < T_STEPS) {
    g_sched[i]               = (float)la;
    g_sched[T_STEPS + i]     = (float)log(-expm1(la));
    g_sched[2 * T_STEPS + i] = (float)run;
    g_sched[3 * T_STEPS + i] = (float)log(-expm1(run));
  }
}

__global__ void build_tab_kernel() {
  int e = blockIdx.x * blockDim.x + threadIdx.x;
  if (e < T_STEPS * NKID) {
    int t = e / NKID, k = e - t * NKID;
    bool t0 = (t == 0);
    int tm1 = t0 ? 0 : t - 1;
    float la = g_sched[t], l1a = g_sched[T_STEPS + t];
    float lca = g_sched[2 * T_STEPS + t], l1ca = g_sched[3 * T_STEPS + t];
    float lca_p = g_sched[2 * T_STEPS + tm1], l1ca_p = g_sched[3 * T_STEPS + tm1];
    float logK = (float)log((double)c_kval[k]);
    // ---- argmax-critical: identical f32 sequence to the verified round-1 kernel ----
    float cb_t = l1ca - logK;
    float ev_h = lae(lca, cb_t);
    float ev_n = lae(NEGL + lca, cb_t);
    // ---- value path: double precision ----
    double cb1 = (double)l1a - (double)logK;
    double q1h = lad((double)la, cb1);
    double q1n = lad((double)NEGL + (double)la, cb1);
    double cbp = (double)l1ca_p - (double)logK;
    double levth = t0 ? 0.0 : lad((double)lca_p, cbp);
    double levtn = t0 ? (double)NEGL : lad((double)NEGL + (double)lca_p, cbp);
    float4* o = g_tab4 + e * 3;
    o[0] = make_float4(ev_h, ev_n, (float)q1h, (float)q1n);
    o[1] = make_float4((float)exp(q1h), (float)exp(q1n), (float)exp(levth), (float)exp(levtn));
    o[2] = make_float4((float)levth, (float)levtn, t0 ? 0.f : (float)exp(cbp), 0.f);
    if (k == 0) g_ecap[t] = t0 ? 1.f : (float)exp((double)lca_p);
  }
  if (e == 0) {
    double lcaT = g_sched[2 * T_STEPS + T_STEPS - 1];
    double l1caT = g_sched[3 * T_STEPS + T_STEPS - 1];
    double s = 0.0;
    for (int f = 0; f < N_FCAT; ++f) {
      double logK = log((double)c_numc[f]);
      double cbT = l1caT - logK;
      double qh = lad(lcaT, cbT);
      double qn = lad((double)NEGL + lcaT, cbT);
      s += exp(qh) * (qh + logK) + (double)(c_numc[f] - 1) * exp(qn) * (qn + logK);
    }
    g_klp = (float)s;
  }
}

// ---- 8-lane reductions via DPP: quad_perm xor1 (0xB1), xor2 (0x4E), row_half_mirror (0x141) ----
__device__ __forceinline__ float osum(float v) {
  v += __int_as_float(__builtin_amdgcn_mov_dpp(__float_as_int(v), 0xB1, 0xF, 0xF, true));
  v += __int_as_float(__builtin_amdgcn_mov_dpp(__float_as_int(v), 0x4E, 0xF, 0xF, true));
  v += __int_as_float(__builtin_amdgcn_mov_dpp(__float_as_int(v), 0x141, 0xF, 0xF, true));
  return v;
}
__device__ __forceinline__ void oargmax(float& smax, int& jm) {
  float os; int oj;
  os = __int_as_float(__builtin_amdgcn_mov_dpp(__float_as_int(smax), 0xB1, 0xF, 0xF, true));
  oj = __builtin_amdgcn_mov_dpp(jm, 0xB1, 0xF, 0xF, true);
  if (os > smax || (os == smax && oj < jm)) { smax = os; jm = oj; }
  os = __int_as_float(__builtin_amdgcn_mov_dpp(__float_as_int(smax), 0x4E, 0xF, 0xF, true));
  oj = __builtin_amdgcn_mov_dpp(jm, 0x4E, 0xF, 0xF, true);
  if (os > smax || (os == smax && oj < jm)) { smax = os; jm = oj; }
  os = __int_as_float(__builtin_amdgcn_mov_dpp(__float_as_int(smax), 0x141, 0xF, 0xF, true));
  oj = __builtin_amdgcn_mov_dpp(jm, 0x141, 0xF, 0xF, true);
  if (os > smax || (os == smax && oj < jm)) { smax = os; jm = oj; }
}

// Small-K feature (NJ<=2), compile-time K, fully unrolled, exp register-cached.
// Decision path bit-identical to verified rounds 1/2/4/5.
template <int K>
__device__ __forceinline__ float feat_body(int g, int off, int h, bool t0, float ecap,
                                           const float* __restrict__ mocat,
                                           const float* __restrict__ urow,
                                           float4 ta, float4 tbv, float4 tc)
{
  constexpr int NJ = (K + 7) / 8;
  static_assert(NJ <= 2, "small-K path only");
  float ev_h = ta.x, ev_n = ta.y, q1h = ta.z, q1n = ta.w;
  float q1he = tbv.x, q1ne = tbv.y, eth = tbv.z, etn = tbv.w;
  float levth = tc.x, levtn = tc.y, cbpe = tc.z;

  float xv[NJ];
  #pragma unroll
  for (int jj = 0; jj < NJ; ++jj) {
    int j = jj * 8 + g;
    int jc = (j < K) ? j : (K - 1);
    xv[jj] = mocat[off + jc];
  }

  // ---- pass 1: sum exp(model_out) + gumbel-score argmax ----
  float s1 = 0.f, smax = NINF;
  int jm = 0x7fffffff;
  #pragma unroll
  for (int jj = 0; jj < NJ; ++jj) {
    int j = jj * 8 + g;
    int jc = (j < K) ? j : (K - 1);
    bool in = (j < K);
    float e = __expf(xv[jj]);
    xv[jj] = e;                               // cache exp for pass 2
    s1 += in ? e : 0.f;
    float u = urow[off + jc];
    u = fminf(fmaxf(u, 1e-30f), 1.0f);
    float gum = -logf(-logf(u));
    float sc = ((j == h) ? ev_h : ev_n) + gum;
    if (in && sc > smax) { smax = sc; jm = j; }
  }
  s1 = osum(s1);
  oargmax(smax, jm);

  float ca = ecap * __builtin_amdgcn_rcpf(s1);  // exp(lca_{t-1}) / sum(exp(mocat))

  // ---- pass 2: E_j = exp(lev_m_j); linear-space accumulation from cached exp ----
  float Sm = 0.f, Bv = 0.f, lmh = 0.f;
  #pragma unroll
  for (int jj = 0; jj < NJ; ++jj) {
    int j = jj * 8 + g;
    bool in = (j < K);
    float E = fmaf(xv[jj], ca, cbpe);        // e^{lr+lca_p} + e^{cb_p}
    float lm = __logf(E);                    // lev_m_j
    float qe = (j == jm) ? q1he : q1ne;      // e^{q1_j}
    Sm = in ? fmaf(E, qe, Sm) : Sm;          // sum e^{un_m}
    float c = ((j == h) ? eth : etn) * qe;   // e^{un_t_j}
    Bv = in ? fmaf(c, lm, Bv) : Bv;          // sum e^{un_t} * lev_m
    lmh += (in && j == h) ? lm : 0.f;
  }
  Sm = osum(Sm); Bv = osum(Bv); lmh = osum(lmh);

  float lse_m = __logf(Sm);
  bool hm = (h == jm);
  float Kf2 = (float)K - 2.f + (hm ? 1.f : 0.f);
  float coefH = eth * (hm ? q1he : q1ne);
  float coefJ = hm ? 0.f : etn * q1he;
  float cn = etn * q1ne;
  float A  = cn * levtn * Kf2 + coefH * levth + coefJ * levtn;  // sum e^{un_t} * levt
  float St = cn * Kf2 + coefH + coefJ;                          // sum e^{un_t}
  float kl = (A - Bv) * __builtin_amdgcn_rcpf(St) - __logf(St) + lse_m;
  float unh = lmh + (hm ? q1h : q1n);
  float dec = lse_m - unh;
  return t0 ? dec : kl;
}

// Big-K feature: runtime K, ROLLED loops (round-4 shape, ~24 VGPR), no exp cache
// (pass 2 reloads x from L1 and recomputes __expf -- identical input, identical value).
__device__ __forceinline__ float big_feat(int g, int K, int off, int h, bool t0, float ecap,
                                          const float* __restrict__ mocat,
                                          const float* __restrict__ urow,
                                          const float4* __restrict__ tb)
{
  float4 ta = tb[0], tbv = tb[1], tc = tb[2];
  float ev_h = ta.x, ev_n = ta.y, q1h = ta.z, q1n = ta.w;
  float q1he = tbv.x, q1ne = tbv.y, eth = tbv.z, etn = tbv.w;
  float levth = tc.x, levtn = tc.y, cbpe = tc.z;

  // ---- pass 1: sum exp(model_out) + gumbel-score argmax ----
  float s1 = 0.f, smax = NINF;
  int jm = 0x7fffffff;
  #pragma unroll 1
  for (int j = g; j < K; j += 8) {
    float x = mocat[off + j];
    s1 += __expf(x);
    float u = urow[off + j];
    u = fminf(fmaxf(u, 1e-30f), 1.0f);
    float gum = -logf(-logf(u));
    float sc = ((j == h) ? ev_h : ev_n) + gum;
    if (sc > smax) { smax = sc; jm = j; }
  }
  s1 = osum(s1);
  oargmax(smax, jm);

  float ca = ecap * __builtin_amdgcn_rcpf(s1);  // exp(lca_{t-1}) / sum(exp(mocat))

  // ---- pass 2: E_j = exp(lev_m_j); linear-space accumulation ----
  float Sm = 0.f, Bv = 0.f, lmh = 0.f;
  #pragma unroll 1
  for (int j = g; j < K; j += 8) {
    float E = fmaf(__expf(mocat[off + j]), ca, cbpe);  // e^{lr+lca_p} + e^{cb_p}
    float lm = __logf(E);                    // lev_m_j
    float qe = (j == jm) ? q1he : q1ne;      // e^{q1_j}
    Sm = fmaf(E, qe, Sm);                    // sum e^{un_m}
    float c = ((j == h) ? eth : etn) * qe;   // e^{un_t_j}
    Bv = fmaf(c, lm, Bv);                    // sum e^{un_t} * lev_m
    lmh += (j == h) ? lm : 0.f;
  }
  Sm = osum(Sm); Bv = osum(Bv); lmh = osum(lmh);

  float lse_m = __logf(Sm);
  bool hm = (h == jm);
  float Kf2 = (float)K - 2.f + (hm ? 1.f : 0.f);
  float coefH = eth * (hm ? q1he : q1ne);
  float coefJ = hm ? 0.f : etn * q1he;
  float cn = etn * q1ne;
  float A  = cn * levtn * Kf2 + coefH * levth + coefJ * levtn;  // sum e^{un_t} * levt
  float St = cn * Kf2 + coefH + coefJ;                          // sum e^{un_t}
  float kl = (A - Bv) * __builtin_amdgcn_rcpf(St) - __logf(St) + lse_m;
  float unh = lmh + (hm ? q1h : q1n);
  float dec = lse_m - unh;
  return t0 ? dec : kl;
}

// One small-K class: hoist the table loads, loop members at runtime
template <int K, int KID, int NM>
__device__ __forceinline__ float do_group(int g, const int (&OS)[NM], const int (&FS)[NM],
                                          const int* __restrict__ xrow, bool t0, float ecap,
                                          const float* __restrict__ mocat,
                                          const float* __restrict__ urow,
                                          const float4* __restrict__ tabt)
{
  const float4* tb = tabt + KID * 3;
  float4 ta = tb[0], tbv = tb[1], tc = tb[2];
  float acc = 0.f;
  #pragma unroll 1
  for (int i = 0; i < NM; ++i)
    acc += feat_body<K>(g, OS[i], xrow[FS[i]], t0, ecap, mocat, urow, ta, tbv, tc);
  return acc;
}

__global__ __launch_bounds__(256) void gmd_kernel(
    const int* __restrict__ xci, const int* __restrict__ tarr,
    const float* __restrict__ noise, const float* __restrict__ ucat,
    const float* __restrict__ mo, float* __restrict__ out)
{
  int tid = blockIdx.x * blockDim.x + threadIdx.x;
  int row = tid >> 3;   // 8 threads per row
  int g   = tid & 7;
  if (row >= B_ROWS) return;

  int t = tarr[row];
  bool t0 = (t == 0);
  float ecap = g_ecap[t];
  const float4* tabt = g_tab4 + (size_t)t * NKID * 3;
  const int* xrow = xci + (size_t)row * N_FCAT;

  const float* morow = mo + (size_t)row * MO_STRIDE;
  const float* mocat = morow + NUM_NUM;
  const float* urow  = ucat + (size_t)row * N_DCAT;

  // Gaussian part: 2 of 16 elements per lane
  float gauss;
  {
    float2 nv = ((const float2*)(noise + (size_t)row * NUM_NUM))[g];
    float2 mv = ((const float2*)morow)[g];
    float d0 = nv.x - mv.x, d1 = nv.y - mv.y;
    gauss = fmaf(d0, d0, d1 * d1);
  }

  float multi = 0.f;
  // ---- small-K features (NJ<=2): unrolled, exp-cached ----
  {
    static constexpr int OS[3] = {0, 2, 210}, FS[3] = {0, 1, 16};
    multi += do_group<2, 0>(g, OS, FS, xrow, t0, ecap, mocat, urow, tabt);
  }
  {
    static constexpr int OS[2] = {4, 212}, FS[2] = {2, 17};
    multi += do_group<3, 1>(g, OS, FS, xrow, t0, ecap, mocat, urow, tabt);
  }
  {
    static constexpr int OS[2] = {7, 215}, FS[2] = {3, 18};
    multi += do_group<4, 2>(g, OS, FS, xrow, t0, ecap, mocat, urow, tabt);
  }
  {
    static constexpr int OS[2] = {11, 219}, FS[2] = {4, 19};
    multi += do_group<5, 3>(g, OS, FS, xrow, t0, ecap, mocat, urow, tabt);
  }
  {
    static constexpr int OS[2] = {16, 224}, FS[2] = {5, 20};
    multi += do_group<6, 4>(g, OS, FS, xrow, t0, ecap, mocat, urow, tabt);
  }
  {
    static constexpr int OS[2] = {22, 230}, FS[2] = {6, 21};
    multi += do_group<8, 5>(g, OS, FS, xrow, t0, ecap, mocat, urow, tabt);
  }
  {
    static constexpr int OS[3] = {30, 40, 238}, FS[3] = {7, 8, 22};
    multi += do_group<10, 6>(g, OS, FS, xrow, t0, ecap, mocat, urow, tabt);
  }
  {
    static constexpr int OS[1] = {50}, FS[1] = {9};
    multi += do_group<12, 7>(g, OS, FS, xrow, t0, ecap, mocat, urow, tabt);
  }
  {
    static constexpr int OS[2] = {62, 78}, FS[2] = {10, 11};
    multi += do_group<16, 8>(g, OS, FS, xrow, t0, ecap, mocat, urow, tabt);
  }
  // ---- big-K features (K=20..50): rolled runtime loop (round-4 shape) ----
  {
    static constexpr int BK[5]   = {20, 24, 32, 40, 50};
    static constexpr int BOFF[5] = {94, 114, 138, 170, 248};
    static constexpr int BKID[5] = {9, 10, 11, 12, 13};
    static constexpr int BFS[5]  = {12, 13, 14, 15, 23};
    #pragma unroll 1
    for (int i = 0; i < 5; ++i)
      multi += big_feat(g, BK[i], BOFF[i], xrow[BFS[i]], t0, ecap, mocat, urow,
                        tabt + BKID[i] * 3);
  }

  gauss = osum(gauss);
  if (g == 0) out[row] = (multi * 1000.f + g_klp) / 24.f + gauss / 16.f;
}

extern "C" void kernel_launch(void* const* d_in, const int* in_sizes, int n_in,
                              void* d_out, int out_size, void* d_ws, size_t ws_size,
                              hipStream_t stream) {
  const int*   xci   = (const int*)d_in[0];
  const int*   tarr  = (const int*)d_in[1];
  const float* noise = (const float*)d_in[2];
  const float* ucat  = (const float*)d_in[3];
  const float* mo    = (const float*)d_in[4];
  float* out = (float*)d_out;
  (void)d_ws; (void)ws_size;

  hipLaunchKernelGGL(build_sched_kernel, dim3(1), dim3(1024), 0, stream);
  hipLaunchKernelGGL(build_tab_kernel, dim3((T_STEPS * NKID + 255) / 256), dim3(256), 0, stream);
  hipLaunchKernelGGL(gmd_kernel, dim3((B_ROWS * 8) / 256), dim3(256), 0, stream,
                     xci, tarr, noise, ucat, mo, out);
}

// Round 10
// 126.708 us; speedup vs baseline: 1.5592x; 1.0211x over previous
//
#include <hip/hip_runtime.h>
#include <math.h>

#define T_STEPS 1000
#define B_ROWS 65536
#define N_FCAT 24
#define N_DCAT 298
#define NUM_NUM 16
#define MO_STRIDE 314
#define NKID 14
#define NEGL -69.07755278982137f   // log(float32(1e-30))
#define NINF -1e38f

__constant__ int c_numc[N_FCAT] = {2,2,3,4,5,6,8,10,10,12,16,16,20,24,32,40,2,3,4,5,6,8,10,50};
__constant__ int c_kval[NKID]   = {2,3,4,5,6,8,10,12,16,20,24,32,40,50};

// persistent module-owned tables, rebuilt deterministically every launch
__device__ float  g_sched[4*T_STEPS];      // LA | L1A | LCA | L1CA
__device__ float  g_ecap[T_STEPS];         // exp(LCA[t-1]) (1.0 at t=0)
__device__ float4 g_tab4[T_STEPS*NKID*3];  // per (t,kidx): 12 floats
__device__ float  g_klp;                   // sum over features of kl_prior

__device__ __forceinline__ float lae(float a, float b) {   // precise f32 (argmax path)
  float m = fmaxf(a, b);
  return m + logf(expf(a - m) + expf(b - m));
}
__device__ __forceinline__ double lad(double a, double b) {
  double m = fmax(a, b);
  return m + log(exp(a - m) + exp(b - m));
}

__global__ void build_sched_kernel() {
  __shared__ double sh[1024];
  int i = threadIdx.x;
  double la = 0.0;
  if (i < T_STEPS) {
    const double PI = 3.14159265358979323846;
    double u0 = (double)i / 1000.0, u1 = (double)(i + 1) / 1000.0;
    double c0 = cos((u0 + 0.008) / 1.008 * PI * 0.5);
    double c1 = cos((u1 + 0.008) / 1.008 * PI * 0.5);
    double beta = 1.0 - (c1 * c1) / (c0 * c0);
    if (beta > 0.2) beta = 0.2;
    la = log(1.0 - beta);
  }
  sh[i] = la;
  __syncthreads();
  double run = la;
  for (int ofs = 1; ofs < 1024; ofs <<= 1) {
    double add = (i >= ofs) ? sh[i - ofs] : 0.0;
    __syncthreads();
    run += add;
    sh[i] = run;
    __syncthreads();
  }
  if (i < T_STEPS) {
    g_sched[i]               = (float)la;
    g_sched[T_STEPS + i]     = (float)log(-expm1(la));
    g_sched[2 * T_STEPS + i] = (float)run;
    g_sched[3 * T_STEPS + i] = (float)log(-expm1(run));
  }
}

__global__ void build_tab_kernel() {
  int e = blockIdx.x * blockDim.x + threadIdx.x;
  if (e < T_STEPS * NKID) {
    int t = e / NKID, k = e - t * NKID;
    bool t0 = (t == 0);
    int tm1 = t0 ? 0 : t - 1;
    float la = g_sched[t], l1a = g_sched[T_STEPS + t];
    float lca = g_sched[2 * T_STEPS + t], l1ca = g_sched[3 * T_STEPS + t];
    float lca_p = g_sched[2 * T_STEPS + tm1], l1ca_p = g_sched[3 * T_STEPS + tm1];
    float logK = (float)log((double)c_kval[k]);
    // ---- argmax-critical: identical f32 sequence to the verified round-1 kernel ----
    float cb_t = l1ca - logK;
    float ev_h = lae(lca, cb_t);
    float ev_n = lae(NEGL + lca, cb_t);
    // ---- value path: double precision ----
    double cb1 = (double)l1a - (double)logK;
    double q1h = lad((double)la, cb1);
    double q1n = lad((double)NEGL + (double)la, cb1);
    double cbp = (double)l1ca_p - (double)logK;
    double levth = t0 ? 0.0 : lad((double)lca_p, cbp);
    double levtn = t0 ? (double)NEGL : lad((double)NEGL + (double)lca_p, cbp);
    float4* o = g_tab4 + e * 3;
    o[0] = make_float4(ev_h, ev_n, (float)q1h, (float)q1n);
    o[1] = make_float4((float)exp(q1h), (float)exp(q1n), (float)exp(levth), (float)exp(levtn));
    o[2] = make_float4((float)levth, (float)levtn, t0 ? 0.f : (float)exp(cbp), 0.f);
    if (k == 0) g_ecap[t] = t0 ? 1.f : (float)exp((double)lca_p);
  }
  if (e == 0) {
    double lcaT = g_sched[2 * T_STEPS + T_STEPS - 1];
    double l1caT = g_sched[3 * T_STEPS + T_STEPS - 1];
    double s = 0.0;
    for (int f = 0; f < N_FCAT; ++f) {
      double logK = log((double)c_numc[f]);
      double cbT = l1caT - logK;
      double qh = lad(lcaT, cbT);
      double qn = lad((double)NEGL + lcaT, cbT);
      s += exp(qh) * (qh + logK) + (double)(c_numc[f] - 1) * exp(qn) * (qn + logK);
    }
    g_klp = (float)s;
  }
}

// ---- 8-lane reductions via DPP: quad_perm xor1 (0xB1), xor2 (0x4E), row_half_mirror (0x141) ----
__device__ __forceinline__ float osum(float v) {
  v += __int_as_float(__builtin_amdgcn_mov_dpp(__float_as_int(v), 0xB1, 0xF, 0xF, true));
  v += __int_as_float(__builtin_amdgcn_mov_dpp(__float_as_int(v), 0x4E, 0xF, 0xF, true));
  v += __int_as_float(__builtin_amdgcn_mov_dpp(__float_as_int(v), 0x141, 0xF, 0xF, true));
  return v;
}
__device__ __forceinline__ void oargmax(float& smax, int& jm) {
  float os; int oj;
  os = __int_as_float(__builtin_amdgcn_mov_dpp(__float_as_int(smax), 0xB1, 0xF, 0xF, true));
  oj = __builtin_amdgcn_mov_dpp(jm, 0xB1, 0xF, 0xF, true);
  if (os > smax || (os == smax && oj < jm)) { smax = os; jm = oj; }
  os = __int_as_float(__builtin_amdgcn_mov_dpp(__float_as_int(smax), 0x4E, 0xF, 0xF, true));
  oj = __builtin_amdgcn_mov_dpp(jm, 0x4E, 0xF, 0xF, true);
  if (os > smax || (os == smax && oj < jm)) { smax = os; jm = oj; }
  os = __int_as_float(__builtin_amdgcn_mov_dpp(__float_as_int(smax), 0x141, 0xF, 0xF, true));
  oj = __builtin_amdgcn_mov_dpp(jm, 0x141, 0xF, 0xF, true);
  if (os > smax || (os == smax && oj < jm)) { smax = os; jm = oj; }
}

// Unrolled feature (NJ<=4, K<=32), compile-time K, exp register-cached across
// passes. Decision path bit-identical to verified rounds 1/2/4/5.
template <int K>
__device__ __forceinline__ float feat_body(int g, int off, int h, bool t0, float ecap,
                                           const float* __restrict__ mocat,
                                           const float* __restrict__ urow,
                                           float4 ta, float4 tbv, float4 tc)
{
  constexpr int NJ = (K + 7) / 8;
  static_assert(NJ <= 4, "unrolled path only for K<=32");
  float ev_h = ta.x, ev_n = ta.y, q1h = ta.z, q1n = ta.w;
  float q1he = tbv.x, q1ne = tbv.y, eth = tbv.z, etn = tbv.w;
  float levth = tc.x, levtn = tc.y, cbpe = tc.z;

  float xv[NJ];
  #pragma unroll
  for (int jj = 0; jj < NJ; ++jj) {
    int j = jj * 8 + g;
    int jc = (j < K) ? j : (K - 1);
    xv[jj] = mocat[off + jc];
  }

  // ---- pass 1: sum exp(model_out) + gumbel-score argmax ----
  float s1 = 0.f, smax = NINF;
  int jm = 0x7fffffff;
  #pragma unroll
  for (int jj = 0; jj < NJ; ++jj) {
    int j = jj * 8 + g;
    int jc = (j < K) ? j : (K - 1);
    bool in = (j < K);
    float e = __expf(xv[jj]);
    xv[jj] = e;                               // cache exp for pass 2
    s1 += in ? e : 0.f;
    float u = urow[off + jc];
    u = fminf(fmaxf(u, 1e-30f), 1.0f);
    float gum = -logf(-logf(u));
    float sc = ((j == h) ? ev_h : ev_n) + gum;
    if (in && sc > smax) { smax = sc; jm = j; }
  }
  s1 = osum(s1);
  oargmax(smax, jm);

  float ca = ecap * __builtin_amdgcn_rcpf(s1);  // exp(lca_{t-1}) / sum(exp(mocat))

  // ---- pass 2: E_j = exp(lev_m_j); linear-space accumulation from cached exp ----
  float Sm = 0.f, Bv = 0.f, lmh = 0.f;
  #pragma unroll
  for (int jj = 0; jj < NJ; ++jj) {
    int j = jj * 8 + g;
    bool in = (j < K);
    float E = fmaf(xv[jj], ca, cbpe);        // e^{lr+lca_p} + e^{cb_p}
    float lm = __logf(E);                    // lev_m_j
    float qe = (j == jm) ? q1he : q1ne;      // e^{q1_j}
    Sm = in ? fmaf(E, qe, Sm) : Sm;          // sum e^{un_m}
    float c = ((j == h) ? eth : etn) * qe;   // e^{un_t_j}
    Bv = in ? fmaf(c, lm, Bv) : Bv;          // sum e^{un_t} * lev_m
    lmh += (in && j == h) ? lm : 0.f;
  }
  Sm = osum(Sm); Bv = osum(Bv); lmh = osum(lmh);

  float lse_m = __logf(Sm);
  bool hm = (h == jm);
  float Kf2 = (float)K - 2.f + (hm ? 1.f : 0.f);
  float coefH = eth * (hm ? q1he : q1ne);
  float coefJ = hm ? 0.f : etn * q1he;
  float cn = etn * q1ne;
  float A  = cn * levtn * Kf2 + coefH * levth + coefJ * levtn;  // sum e^{un_t} * levt
  float St = cn * Kf2 + coefH + coefJ;                          // sum e^{un_t}
  float kl = (A - Bv) * __builtin_amdgcn_rcpf(St) - __logf(St) + lse_m;
  float unh = lmh + (hm ? q1h : q1n);
  float dec = lse_m - unh;
  return t0 ? dec : kl;
}

// Big-K feature (K=40,50 only): runtime K, ROLLED loops, no exp cache (pass 2
// reloads x from L1 and recomputes __expf -- identical input, identical value).
// Keeps register peak low so the whole kernel stays under the 64-VGPR tier.
__device__ __forceinline__ float big_feat(int g, int K, int off, int h, bool t0, float ecap,
                                          const float* __restrict__ mocat,
                                          const float* __restrict__ urow,
                                          const float4* __restrict__ tb)
{
  float4 ta = tb[0], tbv = tb[1], tc = tb[2];
  float ev_h = ta.x, ev_n = ta.y, q1h = ta.z, q1n = ta.w;
  float q1he = tbv.x, q1ne = tbv.y, eth = tbv.z, etn = tbv.w;
  float levth = tc.x, levtn = tc.y, cbpe = tc.z;

  // ---- pass 1: sum exp(model_out) + gumbel-score argmax ----
  float s1 = 0.f, smax = NINF;
  int jm = 0x7fffffff;
  #pragma unroll 1
  for (int j = g; j < K; j += 8) {
    float x = mocat[off + j];
    s1 += __expf(x);
    float u = urow[off + j];
    u = fminf(fmaxf(u, 1e-30f), 1.0f);
    float gum = -logf(-logf(u));
    float sc = ((j == h) ? ev_h : ev_n) + gum;
    if (sc > smax) { smax = sc; jm = j; }
  }
  s1 = osum(s1);
  oargmax(smax, jm);

  float ca = ecap * __builtin_amdgcn_rcpf(s1);  // exp(lca_{t-1}) / sum(exp(mocat))

  // ---- pass 2: E_j = exp(lev_m_j); linear-space accumulation ----
  float Sm = 0.f, Bv = 0.f, lmh = 0.f;
  #pragma unroll 1
  for (int j = g; j < K; j += 8) {
    float E = fmaf(__expf(mocat[off + j]), ca, cbpe);  // e^{lr+lca_p} + e^{cb_p}
    float lm = __logf(E);                    // lev_m_j
    float qe = (j == jm) ? q1he : q1ne;      // e^{q1_j}
    Sm = fmaf(E, qe, Sm);                    // sum e^{un_m}
    float c = ((j == h) ? eth : etn) * qe;   // e^{un_t_j}
    Bv = fmaf(c, lm, Bv);                    // sum e^{un_t} * lev_m
    lmh += (j == h) ? lm : 0.f;
  }
  Sm = osum(Sm); Bv = osum(Bv); lmh = osum(lmh);

  float lse_m = __logf(Sm);
  bool hm = (h == jm);
  float Kf2 = (float)K - 2.f + (hm ? 1.f : 0.f);
  float coefH = eth * (hm ? q1he : q1ne);
  float coefJ = hm ? 0.f : etn * q1he;
  float cn = etn * q1ne;
  float A  = cn * levtn * Kf2 + coefH * levth + coefJ * levtn;  // sum e^{un_t} * levt
  float St = cn * Kf2 + coefH + coefJ;                          // sum e^{un_t}
  float kl = (A - Bv) * __builtin_amdgcn_rcpf(St) - __logf(St) + lse_m;
  float unh = lmh + (hm ? q1h : q1n);
  float dec = lse_m - unh;
  return t0 ? dec : kl;
}

// One K-class: hoist the table loads, loop members at runtime (no extra inlining)
template <int K, int KID, int NM>
__device__ __forceinline__ float do_group(int g, const int (&OS)[NM], const int (&FS)[NM],
                                          const int* __restrict__ xrow, bool t0, float ecap,
                                          const float* __restrict__ mocat,
                                          const float* __restrict__ urow,
                                          const float4* __restrict__ tabt)
{
  const float4* tb = tabt + KID * 3;
  float4 ta = tb[0], tbv = tb[1], tc = tb[2];
  float acc = 0.f;
  #pragma unroll 1
  for (int i = 0; i < NM; ++i)
    acc += feat_body<K>(g, OS[i], xrow[FS[i]], t0, ecap, mocat, urow, ta, tbv, tc);
  return acc;
}

__global__ __launch_bounds__(256) void gmd_kernel(
    const int* __restrict__ xci, const int* __restrict__ tarr,
    const float* __restrict__ noise, const float* __restrict__ ucat,
    const float* __restrict__ mo, float* __restrict__ out)
{
  int tid = blockIdx.x * blockDim.x + threadIdx.x;
  int row = tid >> 3;   // 8 threads per row
  int g   = tid & 7;
  if (row >= B_ROWS) return;

  int t = tarr[row];
  bool t0 = (t == 0);
  float ecap = g_ecap[t];
  const float4* tabt = g_tab4 + (size_t)t * NKID * 3;
  const int* xrow = xci + (size_t)row * N_FCAT;

  const float* morow = mo + (size_t)row * MO_STRIDE;
  const float* mocat = morow + NUM_NUM;
  const float* urow  = ucat + (size_t)row * N_DCAT;

  // Gaussian part: 2 of 16 elements per lane
  float gauss;
  {
    float2 nv = ((const float2*)(noise + (size_t)row * NUM_NUM))[g];
    float2 mv = ((const float2*)morow)[g];
    float d0 = nv.x - mv.x, d1 = nv.y - mv.y;
    gauss = fmaf(d0, d0, d1 * d1);
  }

  float multi = 0.f;
  // ---- unrolled features (K<=32, NJ<=4): exp-cached ----
  {
    static constexpr int OS[3] = {0, 2, 210}, FS[3] = {0, 1, 16};
    multi += do_group<2, 0>(g, OS, FS, xrow, t0, ecap, mocat, urow, tabt);
  }
  {
    static constexpr int OS[2] = {4, 212}, FS[2] = {2, 17};
    multi += do_group<3, 1>(g, OS, FS, xrow, t0, ecap, mocat, urow, tabt);
  }
  {
    static constexpr int OS[2] = {7, 215}, FS[2] = {3, 18};
    multi += do_group<4, 2>(g, OS, FS, xrow, t0, ecap, mocat, urow, tabt);
  }
  {
    static constexpr int OS[2] = {11, 219}, FS[2] = {4, 19};
    multi += do_group<5, 3>(g, OS, FS, xrow, t0, ecap, mocat, urow, tabt);
  }
  {
    static constexpr int OS[2] = {16, 224}, FS[2] = {5, 20};
    multi += do_group<6, 4>(g, OS, FS, xrow, t0, ecap, mocat, urow, tabt);
  }
  {
    static constexpr int OS[2] = {22, 230}, FS[2] = {6, 21};
    multi += do_group<8, 5>(g, OS, FS, xrow, t0, ecap, mocat, urow, tabt);
  }
  {
    static constexpr int OS[3] = {30, 40, 238}, FS[3] = {7, 8, 22};
    multi += do_group<10, 6>(g, OS, FS, xrow, t0, ecap, mocat, urow, tabt);
  }
  {
    static constexpr int OS[1] = {50}, FS[1] = {9};
    multi += do_group<12, 7>(g, OS, FS, xrow, t0, ecap, mocat, urow, tabt);
  }
  {
    static constexpr int OS[2] = {62, 78}, FS[2] = {10, 11};
    multi += do_group<16, 8>(g, OS, FS, xrow, t0, ecap, mocat, urow, tabt);
  }
  {
    static constexpr int OS[1] = {94}, FS[1] = {12};
    multi += do_group<20, 9>(g, OS, FS, xrow, t0, ecap, mocat, urow, tabt);
  }
  {
    static constexpr int OS[1] = {114}, FS[1] = {13};
    multi += do_group<24, 10>(g, OS, FS, xrow, t0, ecap, mocat, urow, tabt);
  }
  {
    static constexpr int OS[1] = {138}, FS[1] = {14};
    multi += do_group<32, 11>(g, OS, FS, xrow, t0, ecap, mocat, urow, tabt);
  }
  // ---- rolled big-K features (K=40,50 only) ----
  {
    static constexpr int BK[2]   = {40, 50};
    static constexpr int BOFF[2] = {170, 248};
    static constexpr int BKID[2] = {12, 13};
    static constexpr int BFS[2]  = {15, 23};
    #pragma unroll 1
    for (int i = 0; i < 2; ++i)
      multi += big_feat(g, BK[i], BOFF[i], xrow[BFS[i]], t0, ecap, mocat, urow,
                        tabt + BKID[i] * 3);
  }

  gauss = osum(gauss);
  if (g == 0) out[row] = (multi * 1000.f + g_klp) / 24.f + gauss / 16.f;
}

extern "C" void kernel_launch(void* const* d_in, const int* in_sizes, int n_in,
                              void* d_out, int out_size, void* d_ws, size_t ws_size,
                              hipStream_t stream) {
  const int*   xci   = (const int*)d_in[0];
  const int*   tarr  = (const int*)d_in[1];
  const float* noise = (const float*)d_in[2];
  const float* ucat  = (const float*)d_in[3];
  const float* mo    = (const float*)d_in[4];
  float* out = (float*)d_out;
  (void)d_ws; (void)ws_size;

  hipLaunchKernelGGL(build_sched_kernel, dim3(1), dim3(1024), 0, stream);
  hipLaunchKernelGGL(build_tab_kernel, dim3((T_STEPS * NKID + 255) / 256), dim3(256), 0, stream);
  hipLaunchKernelGGL(gmd_kernel, dim3((B_ROWS * 8) / 256), dim3(256), 0, stream,
                     xci, tarr, noise, ucat, mo, out);
}